// Round 15
// baseline (205.946 us; speedup 1.0000x reference)
//
#include <hip/hip_runtime.h>
#include <stdint.h>

using i32x4  = __attribute__((ext_vector_type(4)))  int;
using i32x16 = __attribute__((ext_vector_type(16))) int;

#define M_TOT 8192
#define N_TOT 4096
#define K_TOT 4096
#define BM 256
#define BN 256
// K in 64-byte chunks; half j = kc j, j = 0..63.  (R6 GEMM, best = 136.8us,
// at the serial-law floor: T = T_MFMA + T_LDSread + T_stage, MfmaUtil 48.9%.)

__device__ __forceinline__ void gload_lds16(const void* g, void* l) {
  __builtin_amdgcn_global_load_lds(
      (const __attribute__((address_space(1))) void*)(uintptr_t)g,
      (__attribute__((address_space(3))) void*)(uint32_t)(uintptr_t)l,
      16, 0, 0);
}

// Repack int32-widened int8 [rows][4096] into swizzled K-chunk tiles:
// chunk (p,kc) = 16KB: [rr 0..255][64B]; physical 16B-slot sp holds logical
// slot sp ^ ((rr>>1)&3).  GEMM staging is a pure linear copy (rule #21), the
// frag ds_read applies the same XOR.  R15: exactly 2 groups per thread
// (6144x256x2 = 3,145,728 = ntot) + nontemporal input loads (streaming,
// never reused -> keep L2 for the packed output the GEMM reads next).
__global__ void pack_tiles(const int* __restrict__ a32, const int* __restrict__ b32,
                           int8_t* __restrict__ ap, int8_t* __restrict__ bp,
                           int na) {
  const int half = 6144 * 256;
  int idx = blockIdx.x * 256 + threadIdx.x;
#pragma unroll
  for (int rep = 0; rep < 2; ++rep, idx += half) {
    int i = idx;
    const int* src;
    int8_t* dst;
    if (idx < na) { src = a32; dst = ap; }
    else          { src = b32; dst = bp; i = idx - na; }
    int sp = i & 3;
    int rr = (i >> 2) & 255;
    int kc = (i >> 10) & 63;
    int p  = i >> 16;
    int sl = sp ^ ((rr >> 1) & 3);
    const i32x4* s = (const i32x4*)(src + (((size_t)(p * 256 + rr)) << 12) + kc * 64 + sl * 16);
    i32x4 a = __builtin_nontemporal_load(s);
    i32x4 b = __builtin_nontemporal_load(s + 1);
    i32x4 c = __builtin_nontemporal_load(s + 2);
    i32x4 d = __builtin_nontemporal_load(s + 3);
    i32x4 o;
    o.x = (a.x & 255) | ((a.y & 255) << 8) | ((a.z & 255) << 16) | (a.w << 24);
    o.y = (b.x & 255) | ((b.y & 255) << 8) | ((b.z & 255) << 16) | (b.w << 24);
    o.z = (c.x & 255) | ((c.y & 255) << 8) | ((c.z & 255) << 16) | (c.w << 24);
    o.w = (d.x & 255) | ((d.y & 255) << 8) | ((d.z & 255) << 16) | (d.w << 24);
    ((i32x4*)dst)[i] = o;
  }
}

// LDS ring: A halves at region r*16384, B halves at 65536 + r*16384, r = j & 3
#define STAGE_H(jj, R) {                                                   \
    const int8_t* _ga = Asrc + ((size_t)(jj) << 14) + stoff;               \
    char* _da = lds + (((R) & 3) << 14) + w * 2048;                        \
    gload_lds16(_ga, _da); gload_lds16(_ga + 1024, _da + 1024);            \
    const int8_t* _gb = Bsrc + ((size_t)(jj) << 14) + stoff;               \
    char* _db = lds + 65536 + (((R) & 3) << 14) + w * 2048;                \
    gload_lds16(_gb, _db); gload_lds16(_gb + 1024, _db + 1024); }

#define LOAD_FRAGS(DA, DB, R, S) {                                         \
    const int _so = ((((S) << 1) | hi) ^ swz) * 16;                        \
    const char* _pa = lds + (((R) & 3) << 14) + _so;                       \
    const char* _pb = _pa + 65536;                                         \
    _Pragma("unroll")                                                      \
    for (int mi = 0; mi < 4; ++mi) DA[mi] = *(const i32x4*)(_pa + aRow[mi]); \
    _Pragma("unroll")                                                      \
    for (int ni = 0; ni < 2; ++ni) DB[ni] = *(const i32x4*)(_pb + bRow[ni]); }

#define MFMA8(A, B)                                                        \
    _Pragma("unroll")                                                      \
    for (int mi = 0; mi < 4; ++mi)                                         \
    _Pragma("unroll")                                                      \
    for (int ni = 0; ni < 2; ++ni)                                         \
      acc[mi][ni] = __builtin_amdgcn_mfma_i32_32x32x32_i8(A[mi], B[ni], acc[mi][ni], 0, 0, 0);

#define SGB(m, n) __builtin_amdgcn_sched_group_barrier((m), (n), 0)
#define PAIR SGB(0x8, 1); SGB(0x100, 1);

// One half-interval j (region R0 = j&3, next R1 = (j+1)&3).  R6's schedule:
// entry vmcnt retires stage(j+1) (one-deeper, counted); SGB interleaves
// 2 VMEM, 6x{MFMA,DS}, 2 MFMA per half.
#define INTERVAL(j, R0, R1, VM, DO_STAGE, DO_NEXT) {                       \
    asm volatile("s_waitcnt vmcnt(" VM ")" ::: "memory");                  \
    __builtin_amdgcn_s_barrier();                                          \
    __builtin_amdgcn_sched_barrier(0);                                     \
    __builtin_amdgcn_s_setprio(1);                                         \
    if (DO_STAGE) STAGE_H((j) + 3, (R0) + 3);                              \
    LOAD_FRAGS(a1, b1, R0, 1)                                              \
    MFMA8(a0, b0)                                                          \
    if (DO_NEXT) LOAD_FRAGS(a0, b0, R1, 0)                                 \
    MFMA8(a1, b1)                                                          \
    SGB(0x10, 2);                                                          \
    PAIR PAIR PAIR PAIR PAIR PAIR                                          \
    SGB(0x8, 2);                                                           \
    SGB(0x10, 2);                                                          \
    PAIR PAIR PAIR PAIR PAIR PAIR                                          \
    SGB(0x8, 2);                                                           \
    __builtin_amdgcn_s_setprio(0); }

__global__ __launch_bounds__(512, 2) void gemm_w8a8(
    const int8_t* __restrict__ Apack,  // [32 pm][64 kc][256 r][64B] swizzled
    const int8_t* __restrict__ Bpack,  // [16 pn][64 kc][256 r][64B] swizzled
    const int*    __restrict__ bias,
    const float*  __restrict__ alphap,
    const float*  __restrict__ betap,
    int* __restrict__ out)             // [M][N] int32
{
  __shared__ __align__(16) char lds[131072];  // A ring 4x16KB | B ring 4x16KB

  // XCD-aware 8x8 chunking: 32 concurrent wgs/XCD share ~8 A + 4 B panels
  const int bid = blockIdx.x;
  const int xcd = bid & 7, wi = bid >> 3;
  const int tm = (xcd & 3) * 8 + (wi & 7);    // 0..31
  const int tn = (xcd >> 2) * 8 + (wi >> 3);  // 0..15

  const int tid = threadIdx.x;
  const int w   = tid >> 6;
  const int l   = tid & 63;
  const int lr  = l & 31;
  const int hi  = l >> 5;
  const int wr  = w >> 2;   // 0..1
  const int wc  = w & 3;    // 0..3
  const int stoff = w * 2048 + l * 16;

  const int8_t* Asrc = Apack + ((size_t)tm << 20);
  const int8_t* Bsrc = Bpack + ((size_t)tn << 20);

  const int swz = (lr >> 1) & 3;
  int aRow[4], bRow[2];
#pragma unroll
  for (int mi = 0; mi < 4; ++mi) aRow[mi] = (wr * 128 + mi * 32 + lr) * 64;
#pragma unroll
  for (int ni = 0; ni < 2; ++ni) bRow[ni] = (wc * 64 + ni * 32 + lr) * 64;

  i32x16 acc[4][2] = {};
  i32x4 a0[4], b0[2], a1[4], b1[2];

  // prologue: 3 halves in flight, retire half 0, preload its ks0 frags
  STAGE_H(0, 0)
  STAGE_H(1, 1)
  STAGE_H(2, 2)
  asm volatile("s_waitcnt vmcnt(8)" ::: "memory");
  __builtin_amdgcn_s_barrier();
  __builtin_amdgcn_sched_barrier(0);
  LOAD_FRAGS(a0, b0, 0, 0)

  // main: intervals j = 0..59 (steady: vmcnt(4), stage j+3, prefetch j+1 ks0)
  for (int tt = 0; tt < 15; ++tt) {
    const int j0 = tt * 4;
    INTERVAL(j0 + 0, 0, 1, "4", 1, 1)
    INTERVAL(j0 + 1, 1, 2, "4", 1, 1)
    INTERVAL(j0 + 2, 2, 3, "4", 1, 1)
    INTERVAL(j0 + 3, 3, 0, "4", 1, 1)
  }
  // tail: j = 60 (stages 63), 61 (no stage), 62 (drain to 0), 63 (last)
  INTERVAL(60, 0, 1, "4", 1, 1)
  INTERVAL(61, 1, 2, "4", 0, 1)
  INTERVAL(62, 2, 3, "0", 0, 1)
  INTERVAL(63, 3, 0, "0", 0, 0)

  // epilogue: y = clip(rint(alpha*acc + beta*bias)) -> int32
  // C/D 32x32 layout: col = lane&31, row = (reg&3) + 8*(reg>>2) + 4*(lane>>5)
  const float alpha = *alphap;
  const float beta  = *betap;
  const int brow = tm * BM, bcol = tn * BN;
#pragma unroll
  for (int ni = 0; ni < 2; ++ni) {
    const int col = bcol + wc * 64 + ni * 32 + lr;
    const float bb = beta * (float)bias[col];
#pragma unroll
    for (int mi = 0; mi < 4; ++mi) {
      const int rbase = brow + wr * 128 + mi * 32 + 4 * hi;
#pragma unroll
      for (int r = 0; r < 16; ++r) {
        const int row = rbase + (r & 3) + 8 * (r >> 2);
        float v = alpha * (float)acc[mi][ni][r] + bb;
        v = rintf(v);
        v = fminf(127.f, fmaxf(-128.f, v));
        out[(size_t)row * N_TOT + col] = (int)v;
      }
    }
  }
}

extern "C" void kernel_launch(void* const* d_in, const int* in_sizes, int n_in,
                              void* d_out, int out_size, void* d_ws, size_t ws_size,
                              hipStream_t stream) {
  const int*   x32    = (const int*)d_in[0];   // (4,2048,4096) int8 widened to int32
  const int*   w32    = (const int*)d_in[1];   // (4096,4096)
  const int*   bias   = (const int*)d_in[2];   // (1,4096)
  const float* alphap = (const float*)d_in[3];
  const float* betap  = (const float*)d_in[4];
  int* out = (int*)d_out;

  int8_t* xp = (int8_t*)d_ws;                  // Apack: 32 MB
  int8_t* wp = xp + (size_t)M_TOT * K_TOT;     // Bpack: 16 MB (48 MB ws total)

  const int na = (M_TOT * K_TOT) / 16;         // 2,097,152 A groups (of 3,145,728)
  pack_tiles<<<6144, 256, 0, stream>>>(x32, w32, xp, wp, na);

  gemm_w8a8<<<512, 512, 0, stream>>>(xp, wp, bias, alphap, betap, out);
}